// Round 12
// baseline (236.843 us; speedup 1.0000x reference)
//
#include <hip/hip_runtime.h>
#include <hip/hip_bf16.h>

#define B_SZ 32
#define N_SZ 2048
#define H_SZ 1024

typedef float f32x4 __attribute__((ext_vector_type(4)));
typedef short bf16x8 __attribute__((ext_vector_type(8)));

static __device__ __forceinline__ unsigned short f2bf(float f) {
    union { float f; unsigned u; } x; x.f = f;
    unsigned r = x.u + 0x7FFF + ((x.u >> 16) & 1);
    return (unsigned short)(r >> 16);
}

// fast tanh: (e^{2x}-1)/(e^{2x}+1), clamped so e never overflows
static __device__ __forceinline__ float fast_tanh(float x) {
    x = fminf(fmaxf(x, -15.f), 15.f);
    float e = __expf(2.f * x);
    return (e - 1.f) / (e + 1.f);
}

// ---------------- kernel 1: pack Wv f32 -> bf16 in wave-fragment order ----------------
// packed element index: ((((w*32 + k)*4 + t)*64) + lane)*8 + j
//   maps to Wv[g][h], g = w*64 + 16t + (lane&15), h = k*32 + (lane>>4)*8 + j
__global__ __launch_bounds__(256) void pack_wv_kernel(const float* __restrict__ wv,
                                                      short* __restrict__ out) {
    int o8 = blockIdx.x * 256 + threadIdx.x;      // 131072 threads, 8 elems each
    int lane = o8 & 63;
    int t    = (o8 >> 6) & 3;
    int k    = (o8 >> 8) & 31;
    int w    = (o8 >> 13) & 15;
    int g  = w * 64 + 16 * t + (lane & 15);
    int h0 = k * 32 + (lane >> 4) * 8;
    const float* src = wv + (size_t)g * 1024 + h0;
    float4 v0 = *(const float4*)(src);
    float4 v1 = *(const float4*)(src + 4);
    short4 s0, s1;
    s0.x = (short)f2bf(v0.x); s0.y = (short)f2bf(v0.y);
    s0.z = (short)f2bf(v0.z); s0.w = (short)f2bf(v0.w);
    s1.x = (short)f2bf(v1.x); s1.y = (short)f2bf(v1.y);
    s1.z = (short)f2bf(v1.z); s1.w = (short)f2bf(v1.w);
    *(short4*)(out + (size_t)o8 * 8)     = s0;
    *(short4*)(out + (size_t)o8 * 8 + 4) = s1;
}

// ---------------- kernel 2: q_hid = query @ Wq.T + bias ----------------
__global__ __launch_bounds__(256) void qhid_kernel(const float* __restrict__ query,
                                                   const float* __restrict__ Wq,
                                                   const float* __restrict__ bias,
                                                   float* __restrict__ qh) {
    int gb = blockIdx.x * 4;
    __shared__ float wsm[4][1024];
    int t = threadIdx.x;
    for (int i = t; i < 4096; i += 256)
        wsm[i >> 10][i & 1023] = Wq[(size_t)gb * 1024 + i];
    __syncthreads();
    int gi = t >> 6;
    int lane = t & 63;
    int b = lane >> 1;
    int half = lane & 1;
    const float4* q = (const float4*)(query + b * 1024 + half * 512);
    const float4* w = (const float4*)(&wsm[gi][half * 512]);
    float acc = 0.f;
#pragma unroll 8
    for (int h = 0; h < 128; ++h) {
        float4 qv = q[h]; float4 wv = w[h];
        acc += qv.x * wv.x + qv.y * wv.y + qv.z * wv.z + qv.w * wv.w;
    }
    acc += __shfl_xor(acc, 1);
    if (half == 0) qh[b * 1024 + gb + gi] = acc + bias[gb + gi];
}

// MFMA helper: 32 rank-updates of the 8x4 fragment grid
static __device__ __forceinline__ void mm32(const bf16x8 (&a)[8], const bf16x8 (&b)[4],
                                            f32x4 (&acc)[8][4]) {
#pragma unroll
    for (int r = 0; r < 8; ++r)
#pragma unroll
        for (int t = 0; t < 4; ++t)
            acc[r][t] = __builtin_amdgcn_mfma_f32_16x16x32_bf16(a[r], b[t], acc[r][t], 0, 0, 0);
}

// ---------------- kernel 3: fused score GEMM + tanh + Wm dot ----------------
// M=128 tile: block = 128 rows x 512 g (ghalf). 512 threads, 8 waves; wave =
// 128r x 64g (one packed B slot). B volume per unit work HALVED vs M=64
// (total 1.05 GB through L2/fabric - the hypothesized binding resource).
// A panel K-chunked (KC=512, 128KB LDS, one restage barrier). Sibling blocks
// (same panel, other ghalf) are 8 apart in blockIdx -> same XCD under
// round-robin -> panel's 2nd HBM read is an L2 hit.
__global__ __launch_bounds__(512, 2) void fused_score_kernel(
    const float* __restrict__ value, const float* __restrict__ cov,
    const short* __restrict__ wv_pk, const float* __restrict__ qh,
    const float* __restrict__ Wc, const float* __restrict__ Wm,
    float* __restrict__ e_part)
{
    extern __shared__ char smem[];                 // 128KB A-chunk + e_sm[128]
    float* e_sm = (float*)(smem + 131072);

    const int wgid  = blockIdx.x;
    const int p     = ((wgid >> 4) << 3) | (wgid & 7);   // panel 0..511
    const int ghalf = (wgid >> 3) & 1;                   // g half
    const int b     = p >> 4;
    const int n0    = (p & 15) * 128;
    const int tid   = threadIdx.x;

    if (tid < 128) e_sm[tid] = 0.f;

    const float* src = value + ((size_t)(b * N_SZ + n0)) * H_SZ;

    // stage 128 rows x 512 cols chunk (cols [CB, CB+512)) as bf16, swizzled
#define STAGE(CB)                                                              \
    {                                                                          \
        _Pragma("unroll 4")                                                    \
        for (int it = 0; it < 32; ++it) {                                      \
            int e = (it * 512 + tid) * 4;                                      \
            int row = e >> 9;                                                  \
            int col = e & 511;                                                 \
            float4 v = *(const float4*)(src + (size_t)row * H_SZ + (CB) + col);\
            unsigned byteoff = ((unsigned)(row * 1024 + col * 2))              \
                             ^ ((unsigned)((row & 7) << 4));                   \
            short4 s;                                                          \
            s.x = (short)f2bf(v.x); s.y = (short)f2bf(v.y);                    \
            s.z = (short)f2bf(v.z); s.w = (short)f2bf(v.w);                    \
            *(short4*)(smem + byteoff) = s;                                    \
        }                                                                      \
    }

    STAGE(0)
    __syncthreads();

    const int wave = tid >> 6;                   // 0..7
    const int lane = tid & 63;
    const int lrow = lane & 15;
    const int lgrp = lane >> 4;
    const unsigned xorm = (unsigned)((lrow & 7) << 4);
    // chunk-local swizzled bases (row stride 1024B), k-parity split keeps
    // +offset additions carry-free w.r.t. XORed bits 4-6
    const unsigned base_e = ((unsigned)(lrow * 1024 + lgrp * 16)) ^ xorm;      // k even
    const unsigned base_o = ((unsigned)(lrow * 1024 + 64 + lgrp * 16)) ^ xorm; // k odd

    const int slot = ghalf * 8 + wave;           // packed 64-g B slot, 0..15
    const short* bbase = wv_pk + (size_t)slot * 65536 + lane * 8;

    f32x4 acc[8][4];
#pragma unroll
    for (int r = 0; r < 8; ++r)
#pragma unroll
        for (int t = 0; t < 4; ++t) acc[r][t] = (f32x4){0.f, 0.f, 0.f, 0.f};

    // parity double-buffered B fragments (flat k, continuous across chunks)
    bf16x8 bE[4], bO[4];
#pragma unroll
    for (int t = 0; t < 4; ++t) {
        bE[t] = *(const bf16x8*)(bbase + t * 512);
        bO[t] = *(const bf16x8*)(bbase + 2048 + t * 512);
    }
    const short* pE = bbase + 2 * 2048;          // next even k
    const short* pO = bbase + 3 * 2048;          // next odd k

#pragma unroll 1
    for (int c = 0; c < 2; ++c) {
        if (c == 1) {
            __syncthreads();                      // chunk-0 reads done
            STAGE(512)
            __syncthreads();
        }
#pragma unroll 2
        for (int kp = 0; kp < 8; ++kp) {
            bf16x8 afr[8];
            // ---- even sub-step ----
            const unsigned Pe = base_e + (unsigned)(kp * 128);
#pragma unroll
            for (int r = 0; r < 8; ++r)
                afr[r] = *(const bf16x8*)(smem + Pe + (unsigned)(r * 16384));
            __builtin_amdgcn_s_setprio(1);
            mm32(afr, bE, acc);
            __builtin_amdgcn_s_setprio(0);
#pragma unroll
            for (int t = 0; t < 4; ++t)
                bE[t] = *(const bf16x8*)(pE + t * 512);

            // ---- odd sub-step ----
            const unsigned Po = base_o + (unsigned)(kp * 128);
#pragma unroll
            for (int r = 0; r < 8; ++r)
                afr[r] = *(const bf16x8*)(smem + Po + (unsigned)(r * 16384));
            __builtin_amdgcn_s_setprio(1);
            mm32(afr, bO, acc);
            __builtin_amdgcn_s_setprio(0);
#pragma unroll
            for (int t = 0; t < 4; ++t)
                bO[t] = *(const bf16x8*)(pO + t * 512);

            pE += 4096;                           // two k-steps per kp
            pO += 4096;
        }
    }
#undef STAGE

    // epilogue: a = acc + qh + cov*Wc ; e_part += tanh(a)*Wm
    float cv[8][4];
#pragma unroll
    for (int r = 0; r < 8; ++r)
#pragma unroll
        for (int i = 0; i < 4; ++i)
            cv[r][i] = cov[b * N_SZ + n0 + 16 * r + lgrp * 4 + i];

    float s_part[8][4];
#pragma unroll
    for (int r = 0; r < 8; ++r)
#pragma unroll
        for (int i = 0; i < 4; ++i) s_part[r][i] = 0.f;

#pragma unroll
    for (int t = 0; t < 4; ++t) {
        int g = slot * 64 + 16 * t + lrow;
        float qv = qh[b * 1024 + g];
        float wc = Wc[g];
        float wm = Wm[g];
#pragma unroll
        for (int r = 0; r < 8; ++r)
#pragma unroll
            for (int i = 0; i < 4; ++i) {
                float aval = acc[r][t][i] + qv + cv[r][i] * wc;
                s_part[r][i] += fast_tanh(aval) * wm;
            }
    }

    // reduce across the 16 lanes sharing a row, then accumulate into LDS
#pragma unroll
    for (int r = 0; r < 8; ++r)
#pragma unroll
        for (int i = 0; i < 4; ++i) {
            float s = s_part[r][i];
            s += __shfl_xor(s, 1);
            s += __shfl_xor(s, 2);
            s += __shfl_xor(s, 4);
            s += __shfl_xor(s, 8);
            if (lrow == 0) atomicAdd(&e_sm[16 * r + lgrp * 4 + i], s);
        }
    __syncthreads();
    if (tid < 128)
        e_part[((size_t)ghalf * B_SZ + b) * N_SZ + n0 + tid] = e_sm[tid];
}

// ---------------- kernel 4: mask + softmax over n (sums the two e-halves) ----------------
__global__ __launch_bounds__(256) void softmax_kernel(const float* __restrict__ e_part,
                                                      const int* __restrict__ mask,
                                                      const float* __restrict__ bm,
                                                      float* __restrict__ attn_out) {
    int b = blockIdx.x;
    int t = threadIdx.x;
    int wave = t >> 6, lane = t & 63;
    float bmv = bm[0];
    float vals[8];
    float mx = -1e30f;
#pragma unroll
    for (int j = 0; j < 8; ++j) {
        int n = t + 256 * j;
        float ev = e_part[(size_t)b * N_SZ + n]
                 + e_part[((size_t)B_SZ + b) * N_SZ + n] + bmv;
        if (mask[b * N_SZ + n] <= 0) ev = -1e9f;
        vals[j] = ev;
        mx = fmaxf(mx, ev);
    }
#pragma unroll
    for (int m = 1; m < 64; m <<= 1) mx = fmaxf(mx, __shfl_xor(mx, m));
    __shared__ float redmax[4], redsum[4];
    if (lane == 0) redmax[wave] = mx;
    __syncthreads();
    mx = fmaxf(fmaxf(redmax[0], redmax[1]), fmaxf(redmax[2], redmax[3]));
    float sum = 0.f;
#pragma unroll
    for (int j = 0; j < 8; ++j) {
        vals[j] = expf(vals[j] - mx);
        sum += vals[j];
    }
#pragma unroll
    for (int m = 1; m < 64; m <<= 1) sum += __shfl_xor(sum, m);
    if (lane == 0) redsum[wave] = sum;
    __syncthreads();
    sum = redsum[0] + redsum[1] + redsum[2] + redsum[3];
    float inv = 1.f / sum;
#pragma unroll
    for (int j = 0; j < 8; ++j)
        attn_out[b * N_SZ + t + 256 * j] = vals[j] * inv;
}

// ---------------- kernel 5: partial weighted value sum (16 chunks/batch) ----------------
__global__ __launch_bounds__(256) void wsum_partial_kernel(const float* __restrict__ attn,
                                                           const float* __restrict__ value,
                                                           float* __restrict__ partial) {
    int b = blockIdx.x >> 4;
    int c = blockIdx.x & 15;
    int t = threadIdx.x;
    float4 acc = {0.f, 0.f, 0.f, 0.f};
    const float* vbase = value + (size_t)(b * N_SZ + c * 128) * H_SZ;
    const float* abase = attn + b * N_SZ + c * 128;
    for (int n = 0; n < 128; ++n) {
        float a = abase[n];
        if (a != 0.f) {
            float4 v = *(const float4*)(vbase + (size_t)n * H_SZ + t * 4);
            acc.x += a * v.x; acc.y += a * v.y;
            acc.z += a * v.z; acc.w += a * v.w;
        }
    }
    *(float4*)(partial + (size_t)blockIdx.x * H_SZ + t * 4) = acc;
}

// ---------------- kernel 6: reduce partials -> output ----------------
__global__ __launch_bounds__(256) void wsum_reduce_kernel(const float* __restrict__ partial,
                                                          float* __restrict__ out) {
    int i = blockIdx.x * 256 + threadIdx.x;   // 32768 total
    int b = i >> 10;
    int h = i & 1023;
    float s = 0.f;
#pragma unroll
    for (int c = 0; c < 16; ++c) s += partial[(size_t)(b * 16 + c) * H_SZ + h];
    out[i] = s;
}

extern "C" void kernel_launch(void* const* d_in, const int* in_sizes, int n_in,
                              void* d_out, int out_size, void* d_ws, size_t ws_size,
                              hipStream_t stream) {
    const float* query = (const float*)d_in[0];
    const float* value = (const float*)d_in[1];
    const int*   mask  = (const int*)  d_in[2];
    const float* cov   = (const float*)d_in[3];
    const float* Wq    = (const float*)d_in[4];
    const float* Wv    = (const float*)d_in[5];
    const float* Wc    = (const float*)d_in[6];
    const float* bias  = (const float*)d_in[7];
    const float* Wm    = (const float*)d_in[8];
    const float* bm    = (const float*)d_in[9];

    float* out      = (float*)d_out;            // [32*1024] output
    float* attn_out = out + B_SZ * H_SZ;        // [32*2048] attn

    char* ws = (char*)d_ws;
    short* wv_pk   = (short*)ws;                                       // 2 MB
    float* qh      = (float*)(ws + 2 * 1024 * 1024);                   // 128 KB
    float* e_part  = (float*)(ws + 2 * 1024 * 1024 + 128 * 1024);      // 512 KB (2 halves)
    float* partial = (float*)(ws + 2 * 1024 * 1024 + 640 * 1024);      // 2 MB

    pack_wv_kernel<<<512, 256, 0, stream>>>(Wv, wv_pk);
    qhid_kernel<<<256, 256, 0, stream>>>(query, Wq, bias, qh);

    size_t smem = 131072 + 512;
    fused_score_kernel<<<1024, 512, smem, stream>>>(value, cov, wv_pk, qh, Wc, Wm, e_part);

    softmax_kernel<<<B_SZ, 256, 0, stream>>>(e_part, mask, bm, attn_out);
    wsum_partial_kernel<<<B_SZ * 16, 256, 0, stream>>>(attn_out, value, partial);
    wsum_reduce_kernel<<<128, 256, 0, stream>>>(partial, out);
}

// Round 13
// 229.833 us; speedup vs baseline: 1.0305x; 1.0305x over previous
//
#include <hip/hip_runtime.h>
#include <hip/hip_bf16.h>

#define B_SZ 32
#define N_SZ 2048
#define H_SZ 1024

typedef float f32x4 __attribute__((ext_vector_type(4)));
typedef short bf16x8 __attribute__((ext_vector_type(8)));

static __device__ __forceinline__ unsigned short f2bf(float f) {
    union { float f; unsigned u; } x; x.f = f;
    unsigned r = x.u + 0x7FFF + ((x.u >> 16) & 1);
    return (unsigned short)(r >> 16);
}

// fast tanh: (e^{2x}-1)/(e^{2x}+1), clamped so e never overflows
static __device__ __forceinline__ float fast_tanh(float x) {
    x = fminf(fmaxf(x, -15.f), 15.f);
    float e = __expf(2.f * x);
    return (e - 1.f) / (e + 1.f);
}

// ---------------- kernel 1: pack Wv f32 -> bf16 in wave-fragment order ----------------
// packed element index: ((((w*32 + k)*4 + t)*64) + lane)*8 + j
//   maps to Wv[g][h], g = w*64 + 16t + (lane&15), h = k*32 + (lane>>4)*8 + j
__global__ __launch_bounds__(256) void pack_wv_kernel(const float* __restrict__ wv,
                                                      short* __restrict__ out) {
    int o8 = blockIdx.x * 256 + threadIdx.x;      // 131072 threads, 8 elems each
    int lane = o8 & 63;
    int t    = (o8 >> 6) & 3;
    int k    = (o8 >> 8) & 31;
    int w    = (o8 >> 13) & 15;
    int g  = w * 64 + 16 * t + (lane & 15);
    int h0 = k * 32 + (lane >> 4) * 8;
    const float* src = wv + (size_t)g * 1024 + h0;
    float4 v0 = *(const float4*)(src);
    float4 v1 = *(const float4*)(src + 4);
    short4 s0, s1;
    s0.x = (short)f2bf(v0.x); s0.y = (short)f2bf(v0.y);
    s0.z = (short)f2bf(v0.z); s0.w = (short)f2bf(v0.w);
    s1.x = (short)f2bf(v1.x); s1.y = (short)f2bf(v1.y);
    s1.z = (short)f2bf(v1.z); s1.w = (short)f2bf(v1.w);
    *(short4*)(out + (size_t)o8 * 8)     = s0;
    *(short4*)(out + (size_t)o8 * 8 + 4) = s1;
}

// ---------------- kernel 2: q_hid = query @ Wq.T + bias ----------------
__global__ __launch_bounds__(256) void qhid_kernel(const float* __restrict__ query,
                                                   const float* __restrict__ Wq,
                                                   const float* __restrict__ bias,
                                                   float* __restrict__ qh) {
    int gb = blockIdx.x * 4;
    __shared__ float wsm[4][1024];
    int t = threadIdx.x;
    for (int i = t; i < 4096; i += 256)
        wsm[i >> 10][i & 1023] = Wq[(size_t)gb * 1024 + i];
    __syncthreads();
    int gi = t >> 6;
    int lane = t & 63;
    int b = lane >> 1;
    int half = lane & 1;
    const float4* q = (const float4*)(query + b * 1024 + half * 512);
    const float4* w = (const float4*)(&wsm[gi][half * 512]);
    float acc = 0.f;
#pragma unroll 8
    for (int h = 0; h < 128; ++h) {
        float4 qv = q[h]; float4 wv = w[h];
        acc += qv.x * wv.x + qv.y * wv.y + qv.z * wv.z + qv.w * wv.w;
    }
    acc += __shfl_xor(acc, 1);
    if (half == 0) qh[b * 1024 + gb + gi] = acc + bias[gb + gi];
}

// MFMA helper: 16 rank-updates of the 4x4 fragment grid
static __device__ __forceinline__ void mm16(const bf16x8 (&a)[4], const bf16x8 (&b)[4],
                                            f32x4 (&acc)[4][4]) {
#pragma unroll
    for (int r = 0; r < 4; ++r)
#pragma unroll
        for (int t = 0; t < 4; ++t)
            acc[r][t] = __builtin_amdgcn_mfma_f32_16x16x32_bf16(a[r], b[t], acc[r][t], 0, 0, 0);
}

// ---------------- kernel 3: fused score GEMM + tanh + Wm dot ----------------
// 1024 threads (16 waves, 4 waves/SIMD); one 64-row panel per block; full K=1024
// in LDS (staged once). Each wave owns one 64-g slice. CONVOY-BREAKER: wave w
// traverses k in rotated order 2w..31,0..2w-1 (address diversity) and starts
// with a w-proportional s_sleep (temporal diversity) so the 16 identical
// barrier-free k-loops de-phase and overlap MFMA/LDS/L2 across waves.
__global__ __launch_bounds__(1024, 4) void fused_score_kernel(
    const float* __restrict__ value, const float* __restrict__ cov,
    const short* __restrict__ wv_pk, const float* __restrict__ qh,
    const float* __restrict__ Wc, const float* __restrict__ Wm,
    float* __restrict__ e_out)
{
    extern __shared__ char smem[];
    float* e_sm = (float*)(smem + 64 * 1024 * 2);

    const int p   = blockIdx.x;
    const int b   = p >> 5;
    const int n0  = (p & 31) * 64;
    const int tid = threadIdx.x;

    if (tid < 64) e_sm[tid] = 0.f;

    // ---- stage value[b, n0..n0+64, :] as bf16 into swizzled LDS ----
    const float* src = value + ((size_t)(b * N_SZ + n0)) * H_SZ;
#pragma unroll 4
    for (int it = 0; it < 16; ++it) {
        int idx = (it * 1024 + tid) * 4;
        float4 v = *(const float4*)(src + idx);
        int row = idx >> 10;
        int col = idx & 1023;
        unsigned byteoff = (unsigned)(row * 2048 + col * 2) ^ (unsigned)((row & 7) << 4);
        short4 s;
        s.x = (short)f2bf(v.x); s.y = (short)f2bf(v.y);
        s.z = (short)f2bf(v.z); s.w = (short)f2bf(v.w);
        *(short4*)(smem + byteoff) = s;
    }
    __syncthreads();

    const int wave = tid >> 6;                   // 0..15
    const int lane = tid & 63;
    const int lrow = lane & 15;
    const int lgrp = lane >> 4;
    const unsigned xorm = (unsigned)((lrow & 7) << 4);
    // carry-safe swizzled bases: pair-offset adds (bits>=7) never touch XORed bits 4-6
    const unsigned base_e = ((unsigned)(lrow * 2048 + lgrp * 16)) ^ xorm;      // k even
    const unsigned base_o = ((unsigned)(lrow * 2048 + 64 + lgrp * 16)) ^ xorm; // k odd

    const int gbase = wave * 64;                 // this wave's 64-g slice
    const short* bbase = wv_pk + (size_t)wave * 65536 + lane * 8;

    f32x4 acc[4][4];
#pragma unroll
    for (int r = 0; r < 4; ++r)
#pragma unroll
        for (int t = 0; t < 4; ++t) acc[r][t] = (f32x4){0.f, 0.f, 0.f, 0.f};

    // temporal stagger: spread wave k-loop entries across ~2 k-steps
    for (int i = 0; i < wave; ++i) __builtin_amdgcn_s_sleep(1);

    // one k-pair segment: pairs kp0..kp0+npair-1 (k = 2*kp0 .. 2*(kp0+npair)-1)
    auto run_seg = [&](int kp0, int npair) {
        if (npair <= 0) return;
        const short* pC = bbase + kp0 * 4096;     // current k base
        const short* pN = pC + 2048;              // next k base
        bf16x8 bc[4];
#pragma unroll
        for (int t = 0; t < 4; ++t)
            bc[t] = *(const bf16x8*)(pC + t * 512);
        unsigned off = (unsigned)(kp0 * 128);
#pragma unroll 1
        for (int s = 0; s < npair; ++s) {
            bf16x8 bn[4], afr[4];
            // ---- even sub-step ----
#pragma unroll
            for (int t = 0; t < 4; ++t)
                bn[t] = *(const bf16x8*)(pN + t * 512);
#pragma unroll
            for (int r = 0; r < 4; ++r)
                afr[r] = *(const bf16x8*)(smem + base_e + off + (unsigned)(r * 32768));
            __builtin_amdgcn_s_setprio(1);
            mm16(afr, bc, acc);
            __builtin_amdgcn_s_setprio(0);
#pragma unroll
            for (int t = 0; t < 4; ++t) bc[t] = bn[t];
            pN += 2048;
            // ---- odd sub-step ----
#pragma unroll
            for (int t = 0; t < 4; ++t)
                bn[t] = *(const bf16x8*)(pN + t * 512);   // last iter overreads 1 kp (allocated, unused)
#pragma unroll
            for (int r = 0; r < 4; ++r)
                afr[r] = *(const bf16x8*)(smem + base_o + off + (unsigned)(r * 32768));
            __builtin_amdgcn_s_setprio(1);
            mm16(afr, bc, acc);
            __builtin_amdgcn_s_setprio(0);
#pragma unroll
            for (int t = 0; t < 4; ++t) bc[t] = bn[t];
            pN += 2048;
            off += 128;
        }
    };

    run_seg(wave, 16 - wave);     // kp = wave..15
    run_seg(0, wave);             // kp = 0..wave-1

    // epilogue: a = acc + qh + cov*Wc ; e_part += tanh(a)*Wm
    float cv[4][4];
#pragma unroll
    for (int r = 0; r < 4; ++r)
#pragma unroll
        for (int i = 0; i < 4; ++i)
            cv[r][i] = cov[b * N_SZ + n0 + 16 * r + lgrp * 4 + i];

    float s_part[4][4];
#pragma unroll
    for (int r = 0; r < 4; ++r)
#pragma unroll
        for (int i = 0; i < 4; ++i) s_part[r][i] = 0.f;

#pragma unroll
    for (int t = 0; t < 4; ++t) {
        int g = gbase + 16 * t + lrow;
        float qv = qh[b * 1024 + g];
        float wc = Wc[g];
        float wm = Wm[g];
#pragma unroll
        for (int r = 0; r < 4; ++r)
#pragma unroll
            for (int i = 0; i < 4; ++i) {
                float aval = acc[r][t][i] + qv + cv[r][i] * wc;
                s_part[r][i] += fast_tanh(aval) * wm;
            }
    }

    // reduce across the 16 lanes sharing a row, then accumulate into LDS
#pragma unroll
    for (int r = 0; r < 4; ++r)
#pragma unroll
        for (int i = 0; i < 4; ++i) {
            float s = s_part[r][i];
            s += __shfl_xor(s, 1);
            s += __shfl_xor(s, 2);
            s += __shfl_xor(s, 4);
            s += __shfl_xor(s, 8);
            if (lrow == 0) atomicAdd(&e_sm[16 * r + lgrp * 4 + i], s);
        }
    __syncthreads();
    if (tid < 64) e_out[b * N_SZ + n0 + tid] = e_sm[tid];
}

// ---------------- kernel 4: mask + softmax over n ----------------
__global__ __launch_bounds__(256) void softmax_kernel(const float* __restrict__ e,
                                                      const int* __restrict__ mask,
                                                      const float* __restrict__ bm,
                                                      float* __restrict__ attn_out) {
    int b = blockIdx.x;
    int t = threadIdx.x;
    int wave = t >> 6, lane = t & 63;
    float bmv = bm[0];
    float vals[8];
    float mx = -1e30f;
#pragma unroll
    for (int j = 0; j < 8; ++j) {
        int n = t + 256 * j;
        float ev = e[b * N_SZ + n] + bmv;
        if (mask[b * N_SZ + n] <= 0) ev = -1e9f;
        vals[j] = ev;
        mx = fmaxf(mx, ev);
    }
#pragma unroll
    for (int m = 1; m < 64; m <<= 1) mx = fmaxf(mx, __shfl_xor(mx, m));
    __shared__ float redmax[4], redsum[4];
    if (lane == 0) redmax[wave] = mx;
    __syncthreads();
    mx = fmaxf(fmaxf(redmax[0], redmax[1]), fmaxf(redmax[2], redmax[3]));
    float sum = 0.f;
#pragma unroll
    for (int j = 0; j < 8; ++j) {
        vals[j] = expf(vals[j] - mx);
        sum += vals[j];
    }
#pragma unroll
    for (int m = 1; m < 64; m <<= 1) sum += __shfl_xor(sum, m);
    if (lane == 0) redsum[wave] = sum;
    __syncthreads();
    sum = redsum[0] + redsum[1] + redsum[2] + redsum[3];
    float inv = 1.f / sum;
#pragma unroll
    for (int j = 0; j < 8; ++j)
        attn_out[b * N_SZ + t + 256 * j] = vals[j] * inv;
}

// ---------------- kernel 5: partial weighted value sum (16 chunks/batch) ----------------
__global__ __launch_bounds__(256) void wsum_partial_kernel(const float* __restrict__ attn,
                                                           const float* __restrict__ value,
                                                           float* __restrict__ partial) {
    int b = blockIdx.x >> 4;
    int c = blockIdx.x & 15;
    int t = threadIdx.x;
    float4 acc = {0.f, 0.f, 0.f, 0.f};
    const float* vbase = value + (size_t)(b * N_SZ + c * 128) * H_SZ;
    const float* abase = attn + b * N_SZ + c * 128;
    for (int n = 0; n < 128; ++n) {
        float a = abase[n];
        if (a != 0.f) {
            float4 v = *(const float4*)(vbase + (size_t)n * H_SZ + t * 4);
            acc.x += a * v.x; acc.y += a * v.y;
            acc.z += a * v.z; acc.w += a * v.w;
        }
    }
    *(float4*)(partial + (size_t)blockIdx.x * H_SZ + t * 4) = acc;
}

// ---------------- kernel 6: reduce partials -> output ----------------
__global__ __launch_bounds__(256) void wsum_reduce_kernel(const float* __restrict__ partial,
                                                          float* __restrict__ out) {
    int i = blockIdx.x * 256 + threadIdx.x;   // 32768 total
    int b = i >> 10;
    int h = i & 1023;
    float s = 0.f;
#pragma unroll
    for (int c = 0; c < 16; ++c) s += partial[(size_t)(b * 16 + c) * H_SZ + h];
    out[i] = s;
}

extern "C" void kernel_launch(void* const* d_in, const int* in_sizes, int n_in,
                              void* d_out, int out_size, void* d_ws, size_t ws_size,
                              hipStream_t stream) {
    const float* query = (const float*)d_in[0];
    const float* value = (const float*)d_in[1];
    const int*   mask  = (const int*)  d_in[2];
    const float* cov   = (const float*)d_in[3];
    const float* Wq    = (const float*)d_in[4];
    const float* Wv    = (const float*)d_in[5];
    const float* Wc    = (const float*)d_in[6];
    const float* bias  = (const float*)d_in[7];
    const float* Wm    = (const float*)d_in[8];
    const float* bm    = (const float*)d_in[9];

    float* out      = (float*)d_out;            // [32*1024] output
    float* attn_out = out + B_SZ * H_SZ;        // [32*2048] attn

    char* ws = (char*)d_ws;
    short* wv_pk   = (short*)ws;                                       // 2 MB
    float* qh      = (float*)(ws + 2 * 1024 * 1024);                   // 128 KB
    float* e_buf   = (float*)(ws + 2 * 1024 * 1024 + 128 * 1024);      // 256 KB
    float* partial = (float*)(ws + 2 * 1024 * 1024 + 384 * 1024);      // 2 MB

    pack_wv_kernel<<<512, 256, 0, stream>>>(Wv, wv_pk);
    qhid_kernel<<<256, 256, 0, stream>>>(query, Wq, bias, qh);

    size_t smem = 64 * 1024 * 2 + 256;
    fused_score_kernel<<<1024, 1024, smem, stream>>>(value, cov, wv_pk, qh, Wc, Wm, e_buf);

    softmax_kernel<<<B_SZ, 256, 0, stream>>>(e_buf, mask, bm, attn_out);
    wsum_partial_kernel<<<B_SZ * 16, 256, 0, stream>>>(attn_out, value, partial);
    wsum_reduce_kernel<<<128, 256, 0, stream>>>(partial, out);
}